// Round 4
// baseline (624.207 us; speedup 1.0000x reference)
//
#include <hip/hip_runtime.h>
#include <hip/hip_bf16.h>

#define N_NODES 100000
#define N_EDGES 1200000
#define N_GRAPHS 512
#define HID 64
#define IN_DIM 16
#define EPS 1e-5f

#define NB_BUCKETS 391   // ceil(N_NODES / BUCKET_SPAN)
#define BUCKET_SPAN 256  // dst >> 8
#define REGION 4096      // per-bucket region capacity (avg fill ~3069)
#define BIN_TILE 4096    // edges per bin block

typedef _Float16 half4 __attribute__((ext_vector_type(4)));

// ---------------- CSR build (bucketed, LDS-built) ----------------

__global__ void bin_kernel(const int* __restrict__ ei, int* __restrict__ bucketCnt,
                           int* __restrict__ regions) {
    __shared__ int hist[NB_BUCKETS], basem[NB_BUCKETS], cur[NB_BUCKETS];
    int t = threadIdx.x;
    for (int i = t; i < NB_BUCKETS; i += 256) { hist[i] = 0; cur[i] = 0; }
    __syncthreads();
    int e0 = blockIdx.x * BIN_TILE;
    int srcs[16], dsts[16];
#pragma unroll
    for (int i = 0; i < 16; i++) {
        int e = e0 + t + i * 256;
        if (e < N_EDGES) {
            srcs[i] = ei[e];
            dsts[i] = ei[N_EDGES + e];
            atomicAdd(&hist[dsts[i] >> 8], 1);
        } else {
            dsts[i] = -1;
        }
    }
    __syncthreads();
    for (int i = t; i < NB_BUCKETS; i += 256) {
        int h = hist[i];
        basem[i] = h ? atomicAdd(&bucketCnt[i], h) : 0;
    }
    __syncthreads();
#pragma unroll
    for (int i = 0; i < 16; i++) {
        if (dsts[i] >= 0) {
            int b = dsts[i] >> 8;
            int pos = basem[b] + atomicAdd(&cur[b], 1);
            if (pos < REGION)
                regions[b * REGION + pos] = srcs[i] | ((dsts[i] & 255) << 17);
        }
    }
}

__global__ void bucket_scan(const int* __restrict__ bucketCnt, int* __restrict__ bucketBase) {
    __shared__ int buf[512];
    int t = threadIdx.x;
    buf[t] = (t < NB_BUCKETS) ? bucketCnt[t] : 0;
    __syncthreads();
    for (int s = 1; s < 512; s <<= 1) {
        int v = (t >= s) ? buf[t - s] : 0;
        __syncthreads();
        buf[t] += v;
        __syncthreads();
    }
    if (t < NB_BUCKETS) bucketBase[t] = (t == 0) ? 0 : buf[t - 1];
    if (t == 0) bucketBase[NB_BUCKETS] = buf[NB_BUCKETS - 1];
}

__global__ void build_kernel(const int* __restrict__ regions, const int* __restrict__ bucketCnt,
                             const int* __restrict__ bucketBase, int* __restrict__ csrOff,
                             int* __restrict__ csrSrc, float* __restrict__ dis) {
    __shared__ int deg[256], off[256], cur[256];
    __shared__ int slice[REGION];
    int b = blockIdx.x, t = threadIdx.x;
    int cnt = min(bucketCnt[b], REGION);
    int bb = bucketBase[b];
    int nbase = b * BUCKET_SPAN;
    deg[t] = 0;
    __syncthreads();
    for (int i = t; i < cnt; i += 256) {
        int rec = regions[b * REGION + i];
        atomicAdd(&deg[rec >> 17], 1);
    }
    __syncthreads();
    int d = deg[t];
    off[t] = d;
    __syncthreads();
    for (int s = 1; s < 256; s <<= 1) {
        int v = (t >= s) ? off[t - s] : 0;
        __syncthreads();
        off[t] += v;
        __syncthreads();
    }
    int excl = off[t] - d;
    int n = nbase + t;
    if (n < N_NODES) {
        csrOff[n] = bb + excl;
        dis[n] = rsqrtf((float)(d + 1));  // +1 self loop
    }
    if (b == 0 && t == 0) csrOff[N_NODES] = N_EDGES;
    cur[t] = excl;
    __syncthreads();
    for (int i = t; i < cnt; i += 256) {
        int rec = regions[b * REGION + i];
        int pos = atomicAdd(&cur[rec >> 17], 1);
        slice[pos] = rec & 0x1FFFF;
    }
    __syncthreads();
    for (int i = t; i < cnt; i += 256) csrSrc[bb + i] = slice[i];
}

// ---------------- BN statistics ----------------

__global__ void stats_x(const float* __restrict__ x, float* __restrict__ sums,
                        float* __restrict__ sumsq) {
    __shared__ float ls[16], lq[16];
    int t = threadIdx.x;
    if (t < 16) { ls[t] = 0.f; lq[t] = 0.f; }
    __syncthreads();
    float s = 0.f, q = 0.f;
    const int total = N_NODES * IN_DIM;
    for (int i = blockIdx.x * blockDim.x + t; i < total; i += gridDim.x * blockDim.x) {
        float v = x[i];
        s += v; q += v * v;
    }
    int k = t & 15;
    atomicAdd(&ls[k], s);
    atomicAdd(&lq[k], q);
    __syncthreads();
    if (t < 16) { atomicAdd(&sums[t], ls[t]); atomicAdd(&sumsq[t], lq[t]); }
}

__global__ void finalize_bn(const float* __restrict__ sums, const float* __restrict__ sumsq,
                            const float* __restrict__ gamma, const float* __restrict__ beta,
                            float* __restrict__ scale, float* __restrict__ shift, int dim) {
    int t = threadIdx.x;
    if (t < dim) {
        const float invn = 1.0f / (float)N_NODES;
        float m = sums[t] * invn;
        float var = sumsq[t] * invn - m * m;
        float rs = rsqrtf(var + EPS);
        float sc = gamma[t] * rs;
        scale[t] = sc;
        shift[t] = beta[t] - m * sc;
    }
}

// ---------------- GEMMs (BN fused on input read; f16 message output) ----------------

#define GEMM_ROWS 32

__global__ void gemm16_kernel(const float* __restrict__ x, const float* __restrict__ W,
                              const float* __restrict__ scale, const float* __restrict__ shift,
                              const float* __restrict__ dis, _Float16* __restrict__ hout) {
    __shared__ float Ws[IN_DIM][HID];
    __shared__ float xs[GEMM_ROWS][IN_DIM];
    int t = threadIdx.x, f = t & 63, nl = t >> 6;
    for (int i = t; i < IN_DIM * HID; i += 256) Ws[i >> 6][i & 63] = W[i];
    int base = blockIdx.x * GEMM_ROWS;
    for (int i = t; i < GEMM_ROWS * IN_DIM; i += 256) {
        int r = i >> 4, k = i & 15;
        int n = base + r;
        float v = 0.f;
        if (n < N_NODES) v = x[n * IN_DIM + k] * scale[k] + shift[k];
        xs[r][k] = v;
    }
    __syncthreads();
    float acc[8];
#pragma unroll
    for (int r = 0; r < 8; r++) acc[r] = 0.f;
    for (int k = 0; k < IN_DIM; k++) {
        float wk = Ws[k][f];
#pragma unroll
        for (int r = 0; r < 8; r++) acc[r] += xs[r * 4 + nl][k] * wk;
    }
#pragma unroll
    for (int r = 0; r < 8; r++) {
        int n = base + r * 4 + nl;
        if (n < N_NODES) hout[n * HID + f] = (_Float16)(acc[r] * dis[n]);
    }
}

#define G64_ROWS 128
__global__ void gemm64_kernel(const float* __restrict__ hin, const float* __restrict__ W,
                              const float* __restrict__ scale, const float* __restrict__ shift,
                              const float* __restrict__ dis, _Float16* __restrict__ hout) {
    __shared__ float Ws[HID * HID];          // [k][f], f contiguous
    __shared__ float hs[G64_ROWS][HID + 1];  // +1 pad
    int t = threadIdx.x;
    int fg = t & 15;
    int rg = t >> 4;
    int base = blockIdx.x * G64_ROWS;

    {
        const float4* W4 = (const float4*)W;
        float4* Ws4 = (float4*)Ws;
        for (int i = t; i < HID * HID / 4; i += 256) Ws4[i] = W4[i];
    }
    {
        const float4* hin4 = (const float4*)hin;
        const float4* sc4 = (const float4*)scale;
        const float4* sh4 = (const float4*)shift;
        for (int i = t; i < G64_ROWS * 16; i += 256) {
            int r = i >> 4, c = i & 15;
            int n = base + r;
            float4 v = make_float4(0.f, 0.f, 0.f, 0.f);
            if (n < N_NODES) {
                float4 h = hin4[n * 16 + c];
                float4 s = sc4[c], bsh = sh4[c];
                v.x = fmaxf(h.x * s.x + bsh.x, 0.f);
                v.y = fmaxf(h.y * s.y + bsh.y, 0.f);
                v.z = fmaxf(h.z * s.z + bsh.z, 0.f);
                v.w = fmaxf(h.w * s.w + bsh.w, 0.f);
            }
            hs[r][c * 4 + 0] = v.x;
            hs[r][c * 4 + 1] = v.y;
            hs[r][c * 4 + 2] = v.z;
            hs[r][c * 4 + 3] = v.w;
        }
    }
    __syncthreads();

    float4 acc[8];
#pragma unroll
    for (int r = 0; r < 8; r++) acc[r] = make_float4(0.f, 0.f, 0.f, 0.f);
    const float4* Ws4 = (const float4*)Ws;
    for (int k = 0; k < HID; k++) {
        float4 wk = Ws4[k * 16 + fg];
#pragma unroll
        for (int r = 0; r < 8; r++) {
            float h = hs[rg * 8 + r][k];
            acc[r].x += h * wk.x;
            acc[r].y += h * wk.y;
            acc[r].z += h * wk.z;
            acc[r].w += h * wk.w;
        }
    }
    half4* hout4 = (half4*)hout;
#pragma unroll
    for (int r = 0; r < 8; r++) {
        int n = base + rg * 8 + r;
        if (n < N_NODES) {
            float dsc = dis[n];
            half4 o;
            o.x = (_Float16)(acc[r].x * dsc);
            o.y = (_Float16)(acc[r].y * dsc);
            o.z = (_Float16)(acc[r].z * dsc);
            o.w = (_Float16)(acc[r].w * dsc);
            hout4[n * 16 + fg] = o;
        }
    }
}

// ---------------- Aggregation (CSR gather, f16 rows, 8 in flight) ----------------

__global__ void aggregate_kernel(const half4* __restrict__ hwh, const int* __restrict__ csrOff,
                                 const int* __restrict__ csrSrc, const float* __restrict__ dis,
                                 const float* __restrict__ bias, float4* __restrict__ y4,
                                 float* __restrict__ sums, float* __restrict__ sumsq) {
    const int lane = threadIdx.x & 63;
    const int wid = threadIdx.x >> 6;
    const int q = lane >> 4;   // edge slot 0..3
    const int fl = lane & 15;  // half4 column within the 64-half row
    const int wave = blockIdx.x * 4 + wid;
    const int nwaves = gridDim.x * 4;

    const float4 bias4 = ((const float4*)bias)[fl];
    float4 s_acc = make_float4(0.f, 0.f, 0.f, 0.f);
    float4 q_acc = make_float4(0.f, 0.f, 0.f, 0.f);

    for (int n = wave; n < N_NODES; n += nwaves) {
        int beg = csrOff[n], end = csrOff[n + 1];
        float d = dis[n];
        float4 acc = make_float4(0.f, 0.f, 0.f, 0.f);
        if (q == 0) {
            half4 s = hwh[n * 16 + fl];  // self loop
            acc.x = (float)s.x; acc.y = (float)s.y;
            acc.z = (float)s.z; acc.w = (float)s.w;
        }
        int e = beg + q;
        int i0 = -1, i1 = -1;
        if (e < end) i0 = csrSrc[e];
        if (e + 4 < end) i1 = csrSrc[e + 4];
        while (e < end) {
            int j0 = i0, j1 = i1;
            int en = e + 8;
            i0 = (en < end) ? csrSrc[en] : -1;
            i1 = (en + 4 < end) ? csrSrc[en + 4] : -1;
            half4 h0 = hwh[j0 * 16 + fl];  // j0 valid whenever e < end
            if (j1 >= 0) {
                half4 h1 = hwh[j1 * 16 + fl];
                acc.x += (float)h1.x; acc.y += (float)h1.y;
                acc.z += (float)h1.z; acc.w += (float)h1.w;
            }
            acc.x += (float)h0.x; acc.y += (float)h0.y;
            acc.z += (float)h0.z; acc.w += (float)h0.w;
            e = en;
        }
        acc.x += __shfl_xor(acc.x, 16, 64);
        acc.y += __shfl_xor(acc.y, 16, 64);
        acc.z += __shfl_xor(acc.z, 16, 64);
        acc.w += __shfl_xor(acc.w, 16, 64);
        acc.x += __shfl_xor(acc.x, 32, 64);
        acc.y += __shfl_xor(acc.y, 32, 64);
        acc.z += __shfl_xor(acc.z, 32, 64);
        acc.w += __shfl_xor(acc.w, 32, 64);
        if (q == 0) {
            float4 val;
            val.x = acc.x * d + bias4.x;
            val.y = acc.y * d + bias4.y;
            val.z = acc.z * d + bias4.z;
            val.w = acc.w * d + bias4.w;
            y4[n * 16 + fl] = val;
            s_acc.x += val.x; s_acc.y += val.y; s_acc.z += val.z; s_acc.w += val.w;
            q_acc.x += val.x * val.x; q_acc.y += val.y * val.y;
            q_acc.z += val.z * val.z; q_acc.w += val.w * val.w;
        }
    }
    __shared__ float ls[4][64], lq[4][64];
    ls[wid][lane] = 0.f;
    lq[wid][lane] = 0.f;
    if (q == 0) {
        ls[wid][fl * 4 + 0] = s_acc.x; ls[wid][fl * 4 + 1] = s_acc.y;
        ls[wid][fl * 4 + 2] = s_acc.z; ls[wid][fl * 4 + 3] = s_acc.w;
        lq[wid][fl * 4 + 0] = q_acc.x; lq[wid][fl * 4 + 1] = q_acc.y;
        lq[wid][fl * 4 + 2] = q_acc.z; lq[wid][fl * 4 + 3] = q_acc.w;
    }
    __syncthreads();
    if (wid == 0) {
        float S = ls[0][lane] + ls[1][lane] + ls[2][lane] + ls[3][lane];
        float Q = lq[0][lane] + lq[1][lane] + lq[2][lane] + lq[3][lane];
        atomicAdd(&sums[lane], S);
        atomicAdd(&sumsq[lane], Q);
    }
}

// ---------------- Pool + head ----------------

#define POOL_CHUNK 256
__global__ void pool_kernel(const float* __restrict__ y, const int* __restrict__ batch,
                            const float* __restrict__ scale, const float* __restrict__ shift,
                            float* __restrict__ pool, float* __restrict__ cnt) {
    int f = threadIdx.x & 63;
    int nl = threadIdx.x >> 6;
    int base = blockIdx.x * POOL_CHUNK;
    int endn = min(base + POOL_CHUNK, N_NODES);
    float sc = scale[f], sh = shift[f];
    int g_cur = -1;
    float acc = 0.f;
    float c_acc = 0.f;
    for (int n = base + nl; n < endn; n += 4) {
        int g = batch[n];
        float v = fmaxf(y[n * HID + f] * sc + sh, 0.f);
        if (g != g_cur) {
            if (g_cur >= 0) {
                atomicAdd(&pool[g_cur * HID + f], acc);
                if (f == 0) atomicAdd(&cnt[g_cur], c_acc);
            }
            g_cur = g;
            acc = 0.f;
            c_acc = 0.f;
        }
        acc += v;
        c_acc += 1.f;
    }
    if (g_cur >= 0) {
        atomicAdd(&pool[g_cur * HID + f], acc);
        if (f == 0) atomicAdd(&cnt[g_cur], c_acc);
    }
}

__global__ void head_kernel(const float* __restrict__ pool, const float* __restrict__ cnt,
                            const float* __restrict__ Wc1, const float* __restrict__ bc1,
                            const float* __restrict__ Wc2, const float* __restrict__ bc2,
                            float* __restrict__ out) {
    int g = blockIdx.x;
    int f = threadIdx.x;  // 64 threads
    __shared__ float p[64], z[64];
    float c = fmaxf(cnt[g], 1.0f);
    p[f] = pool[g * HID + f] / c;
    __syncthreads();
    float acc = bc1[f];
    for (int k = 0; k < 64; k++) acc += p[k] * Wc1[k * 64 + f];
    z[f] = fmaxf(acc, 0.f);
    __syncthreads();
    if (f < 2) {
        float o = bc2[f];
        for (int k = 0; k < 64; k++) o += z[k] * Wc2[k * 2 + f];
        out[g * 2 + f] = o;
    }
}

// ---------------- launch ----------------

extern "C" void kernel_launch(void* const* d_in, const int* in_sizes, int n_in,
                              void* d_out, int out_size, void* d_ws, size_t ws_size,
                              hipStream_t stream) {
    const float* x      = (const float*)d_in[0];
    const int*   ei     = (const int*)d_in[1];
    const int*   batch  = (const int*)d_in[2];
    const float* bn_in_g = (const float*)d_in[3];
    const float* bn_in_b = (const float*)d_in[4];
    const float* W0 = (const float*)d_in[5];
    const float* b0 = (const float*)d_in[6];
    const float* g0 = (const float*)d_in[7];
    const float* be0 = (const float*)d_in[8];
    const float* W1 = (const float*)d_in[9];
    const float* b1 = (const float*)d_in[10];
    const float* g1 = (const float*)d_in[11];
    const float* be1 = (const float*)d_in[12];
    const float* W2 = (const float*)d_in[13];
    const float* b2 = (const float*)d_in[14];
    const float* g2 = (const float*)d_in[15];
    const float* be2 = (const float*)d_in[16];
    const float* Wc1 = (const float*)d_in[17];
    const float* bc1 = (const float*)d_in[18];
    const float* Wc2 = (const float*)d_in[19];
    const float* bc2 = (const float*)d_in[20];
    float* out = (float*)d_out;

    char* w = (char*)d_ws;
    size_t off = 0;
    auto take = [&](size_t bytes) {
        size_t r = off;
        off += (bytes + 255) & ~(size_t)255;
        return r;
    };
    // ---- zero region (one memset) ----
    float* stats  = (float*)(w + take(4 * 256 * 4));
    float* pool   = (float*)(w + take((size_t)N_GRAPHS * HID * 4));
    float* cnt    = (float*)(w + take((size_t)N_GRAPHS * 4));
    int* bucketCnt = (int*)(w + take((size_t)NB_BUCKETS * 4));
    size_t zero_end = off;
    // ---- rest ----
    float* dis    = (float*)(w + take((size_t)N_NODES * 4));
    int* csrOff   = (int*)(w + take((size_t)(N_NODES + 1) * 4));
    int* csrSrc   = (int*)(w + take((size_t)N_EDGES * 4));
    int* bucketBase = (int*)(w + take((size_t)(NB_BUCKETS + 1) * 4));
    _Float16* hwBuf = (_Float16*)(w + take((size_t)N_NODES * HID * 2));  // f16 messages
    float* yBuf   = (float*)(w + take((size_t)N_NODES * HID * 4));       // f32 activations
    int* regions  = (int*)hwBuf;  // alias: regions (6.4 MB) used only before gemm16
    (void)ws_size; (void)n_in; (void)in_sizes; (void)out_size;

    hipMemsetAsync(w, 0, zero_end, stream);

    const int nbBin  = (N_EDGES + BIN_TILE - 1) / BIN_TILE;  // 293
    const int nbG16  = (N_NODES + GEMM_ROWS - 1) / GEMM_ROWS;
    const int nbG64  = (N_NODES + G64_ROWS - 1) / G64_ROWS;
    const int nbAgg  = 4096;

    // CSR build (bucketed)
    bin_kernel<<<nbBin, 256, 0, stream>>>(ei, bucketCnt, regions);
    bucket_scan<<<1, 512, 0, stream>>>(bucketCnt, bucketBase);
    build_kernel<<<NB_BUCKETS, 256, 0, stream>>>(regions, bucketCnt, bucketBase,
                                                 csrOff, csrSrc, dis);

    float* s0 = stats + 0 * 256;
    float* s1 = stats + 1 * 256;
    float* s2 = stats + 2 * 256;
    float* s3 = stats + 3 * 256;

    // input BN
    stats_x<<<256, 256, 0, stream>>>(x, s0, s0 + 64);
    finalize_bn<<<1, 64, 0, stream>>>(s0, s0 + 64, bn_in_g, bn_in_b, s0 + 128, s0 + 192, IN_DIM);

    // layer 0
    gemm16_kernel<<<nbG16, 256, 0, stream>>>(x, W0, s0 + 128, s0 + 192, dis, hwBuf);
    aggregate_kernel<<<nbAgg, 256, 0, stream>>>((const half4*)hwBuf, csrOff, csrSrc, dis, b0,
                                                (float4*)yBuf, s1, s1 + 64);
    finalize_bn<<<1, 64, 0, stream>>>(s1, s1 + 64, g0, be0, s1 + 128, s1 + 192, HID);

    // layer 1
    gemm64_kernel<<<nbG64, 256, 0, stream>>>(yBuf, W1, s1 + 128, s1 + 192, dis, hwBuf);
    aggregate_kernel<<<nbAgg, 256, 0, stream>>>((const half4*)hwBuf, csrOff, csrSrc, dis, b1,
                                                (float4*)yBuf, s2, s2 + 64);
    finalize_bn<<<1, 64, 0, stream>>>(s2, s2 + 64, g1, be1, s2 + 128, s2 + 192, HID);

    // layer 2
    gemm64_kernel<<<nbG64, 256, 0, stream>>>(yBuf, W2, s2 + 128, s2 + 192, dis, hwBuf);
    aggregate_kernel<<<nbAgg, 256, 0, stream>>>((const half4*)hwBuf, csrOff, csrSrc, dis, b2,
                                                (float4*)yBuf, s3, s3 + 64);
    finalize_bn<<<1, 64, 0, stream>>>(s3, s3 + 64, g2, be2, s3 + 128, s3 + 192, HID);

    // pool + head
    const int nbPool = (N_NODES + POOL_CHUNK - 1) / POOL_CHUNK;
    pool_kernel<<<nbPool, 256, 0, stream>>>(yBuf, batch, s3 + 128, s3 + 192, pool, cnt);
    head_kernel<<<N_GRAPHS, 64, 0, stream>>>(pool, cnt, Wc1, bc1, Wc2, bc2, out);
}

// Round 5
// 600.538 us; speedup vs baseline: 1.0394x; 1.0394x over previous
//
#include <hip/hip_runtime.h>
#include <hip/hip_bf16.h>

#define N_NODES 100000
#define N_EDGES 1200000
#define N_GRAPHS 512
#define HID 64
#define IN_DIM 16
#define EPS 1e-5f

#define NB_BUCKETS 391   // ceil(N_NODES / BUCKET_SPAN)
#define BUCKET_SPAN 256  // dst >> 8
#define REGION 4096      // per-bucket region capacity (avg fill ~3069)
#define BIN_TILE 4096    // edges per bin block

typedef _Float16 half4 __attribute__((ext_vector_type(4)));
typedef _Float16 half8 __attribute__((ext_vector_type(8)));

// ---------------- CSR build (bucketed, LDS-built) ----------------

__global__ void bin_kernel(const int* __restrict__ ei, int* __restrict__ bucketCnt,
                           int* __restrict__ regions) {
    __shared__ int hist[NB_BUCKETS], basem[NB_BUCKETS], cur[NB_BUCKETS];
    int t = threadIdx.x;
    for (int i = t; i < NB_BUCKETS; i += 256) { hist[i] = 0; cur[i] = 0; }
    __syncthreads();
    int e0 = blockIdx.x * BIN_TILE;
    int srcs[16], dsts[16];
#pragma unroll
    for (int i = 0; i < 16; i++) {
        int e = e0 + t + i * 256;
        if (e < N_EDGES) {
            srcs[i] = ei[e];
            dsts[i] = ei[N_EDGES + e];
            atomicAdd(&hist[dsts[i] >> 8], 1);
        } else {
            dsts[i] = -1;
        }
    }
    __syncthreads();
    for (int i = t; i < NB_BUCKETS; i += 256) {
        int h = hist[i];
        basem[i] = h ? atomicAdd(&bucketCnt[i], h) : 0;
    }
    __syncthreads();
#pragma unroll
    for (int i = 0; i < 16; i++) {
        if (dsts[i] >= 0) {
            int b = dsts[i] >> 8;
            int pos = basem[b] + atomicAdd(&cur[b], 1);
            if (pos < REGION)
                regions[b * REGION + pos] = srcs[i] | ((dsts[i] & 255) << 17);
        }
    }
}

__global__ void bucket_scan(const int* __restrict__ bucketCnt, int* __restrict__ bucketBase) {
    __shared__ int buf[512];
    int t = threadIdx.x;
    buf[t] = (t < NB_BUCKETS) ? bucketCnt[t] : 0;
    __syncthreads();
    for (int s = 1; s < 512; s <<= 1) {
        int v = (t >= s) ? buf[t - s] : 0;
        __syncthreads();
        buf[t] += v;
        __syncthreads();
    }
    if (t < NB_BUCKETS) bucketBase[t] = (t == 0) ? 0 : buf[t - 1];
    if (t == 0) bucketBase[NB_BUCKETS] = buf[NB_BUCKETS - 1];
}

__global__ void build_kernel(const int* __restrict__ regions, const int* __restrict__ bucketCnt,
                             const int* __restrict__ bucketBase, int* __restrict__ csrOff,
                             int* __restrict__ csrSrc, float* __restrict__ dis) {
    __shared__ int deg[256], off[256], cur[256];
    __shared__ int slice[REGION];
    int b = blockIdx.x, t = threadIdx.x;
    int cnt = min(bucketCnt[b], REGION);
    int bb = bucketBase[b];
    int nbase = b * BUCKET_SPAN;
    deg[t] = 0;
    __syncthreads();
    for (int i = t; i < cnt; i += 256) {
        int rec = regions[b * REGION + i];
        atomicAdd(&deg[rec >> 17], 1);
    }
    __syncthreads();
    int d = deg[t];
    off[t] = d;
    __syncthreads();
    for (int s = 1; s < 256; s <<= 1) {
        int v = (t >= s) ? off[t - s] : 0;
        __syncthreads();
        off[t] += v;
        __syncthreads();
    }
    int excl = off[t] - d;
    int n = nbase + t;
    if (n < N_NODES) {
        csrOff[n] = bb + excl;
        dis[n] = rsqrtf((float)(d + 1));  // +1 self loop
    }
    if (b == 0 && t == 0) csrOff[N_NODES] = N_EDGES;
    cur[t] = excl;
    __syncthreads();
    for (int i = t; i < cnt; i += 256) {
        int rec = regions[b * REGION + i];
        int pos = atomicAdd(&cur[rec >> 17], 1);
        slice[pos] = rec & 0x1FFFF;
    }
    __syncthreads();
    for (int i = t; i < cnt; i += 256) csrSrc[bb + i] = slice[i];
}

// ---------------- BN statistics (also zeroes the dummy gather row) ----------------

__global__ void stats_x(const float* __restrict__ x, float* __restrict__ sums,
                        float* __restrict__ sumsq, _Float16* __restrict__ hwBuf) {
    __shared__ float ls[16], lq[16];
    int t = threadIdx.x;
    if (blockIdx.x == 0 && t < 16)
        ((half4*)(hwBuf + (size_t)N_NODES * HID))[t] = (half4)(_Float16)0.f;
    if (t < 16) { ls[t] = 0.f; lq[t] = 0.f; }
    __syncthreads();
    float s = 0.f, q = 0.f;
    const int total = N_NODES * IN_DIM;
    for (int i = blockIdx.x * blockDim.x + t; i < total; i += gridDim.x * blockDim.x) {
        float v = x[i];
        s += v; q += v * v;
    }
    int k = t & 15;
    atomicAdd(&ls[k], s);
    atomicAdd(&lq[k], q);
    __syncthreads();
    if (t < 16) { atomicAdd(&sums[t], ls[t]); atomicAdd(&sumsq[t], lq[t]); }
}

__global__ void finalize_bn(const float* __restrict__ sums, const float* __restrict__ sumsq,
                            const float* __restrict__ gamma, const float* __restrict__ beta,
                            float* __restrict__ scale, float* __restrict__ shift, int dim) {
    int t = threadIdx.x;
    if (t < dim) {
        const float invn = 1.0f / (float)N_NODES;
        float m = sums[t] * invn;
        float var = sumsq[t] * invn - m * m;
        float rs = rsqrtf(var + EPS);
        float sc = gamma[t] * rs;
        scale[t] = sc;
        shift[t] = beta[t] - m * sc;
    }
}

// ---------------- GEMMs (BN fused on input read; f16 message output) ----------------

#define GEMM_ROWS 32

__global__ void gemm16_kernel(const float* __restrict__ x, const float* __restrict__ W,
                              const float* __restrict__ scale, const float* __restrict__ shift,
                              const float* __restrict__ dis, _Float16* __restrict__ hout) {
    __shared__ float Ws[IN_DIM][HID];
    __shared__ float xs[GEMM_ROWS][IN_DIM];
    int t = threadIdx.x, f = t & 63, nl = t >> 6;
    for (int i = t; i < IN_DIM * HID; i += 256) Ws[i >> 6][i & 63] = W[i];
    int base = blockIdx.x * GEMM_ROWS;
    for (int i = t; i < GEMM_ROWS * IN_DIM; i += 256) {
        int r = i >> 4, k = i & 15;
        int n = base + r;
        float v = 0.f;
        if (n < N_NODES) v = x[n * IN_DIM + k] * scale[k] + shift[k];
        xs[r][k] = v;
    }
    __syncthreads();
    float acc[8];
#pragma unroll
    for (int r = 0; r < 8; r++) acc[r] = 0.f;
    for (int k = 0; k < IN_DIM; k++) {
        float wk = Ws[k][f];
#pragma unroll
        for (int r = 0; r < 8; r++) acc[r] += xs[r * 4 + nl][k] * wk;
    }
#pragma unroll
    for (int r = 0; r < 8; r++) {
        int n = base + r * 4 + nl;
        if (n < N_NODES) hout[n * HID + f] = (_Float16)(acc[r] * dis[n]);
    }
}

#define G64_ROWS 128
__global__ void gemm64_kernel(const float* __restrict__ hin, const float* __restrict__ W,
                              const float* __restrict__ scale, const float* __restrict__ shift,
                              const float* __restrict__ dis, _Float16* __restrict__ hout) {
    __shared__ float Ws[HID * HID];          // [k][f], f contiguous
    __shared__ float hs[G64_ROWS][HID + 1];  // +1 pad
    int t = threadIdx.x;
    int fg = t & 15;
    int rg = t >> 4;
    int base = blockIdx.x * G64_ROWS;

    {
        const float4* W4 = (const float4*)W;
        float4* Ws4 = (float4*)Ws;
        for (int i = t; i < HID * HID / 4; i += 256) Ws4[i] = W4[i];
    }
    {
        const float4* hin4 = (const float4*)hin;
        const float4* sc4 = (const float4*)scale;
        const float4* sh4 = (const float4*)shift;
        for (int i = t; i < G64_ROWS * 16; i += 256) {
            int r = i >> 4, c = i & 15;
            int n = base + r;
            float4 v = make_float4(0.f, 0.f, 0.f, 0.f);
            if (n < N_NODES) {
                float4 h = hin4[n * 16 + c];
                float4 s = sc4[c], bsh = sh4[c];
                v.x = fmaxf(h.x * s.x + bsh.x, 0.f);
                v.y = fmaxf(h.y * s.y + bsh.y, 0.f);
                v.z = fmaxf(h.z * s.z + bsh.z, 0.f);
                v.w = fmaxf(h.w * s.w + bsh.w, 0.f);
            }
            hs[r][c * 4 + 0] = v.x;
            hs[r][c * 4 + 1] = v.y;
            hs[r][c * 4 + 2] = v.z;
            hs[r][c * 4 + 3] = v.w;
        }
    }
    __syncthreads();

    float4 acc[8];
#pragma unroll
    for (int r = 0; r < 8; r++) acc[r] = make_float4(0.f, 0.f, 0.f, 0.f);
    const float4* Ws4 = (const float4*)Ws;
    for (int k = 0; k < HID; k++) {
        float4 wk = Ws4[k * 16 + fg];
#pragma unroll
        for (int r = 0; r < 8; r++) {
            float h = hs[rg * 8 + r][k];
            acc[r].x += h * wk.x;
            acc[r].y += h * wk.y;
            acc[r].z += h * wk.z;
            acc[r].w += h * wk.w;
        }
    }
    half4* hout4 = (half4*)hout;
#pragma unroll
    for (int r = 0; r < 8; r++) {
        int n = base + rg * 8 + r;
        if (n < N_NODES) {
            float dsc = dis[n];
            half4 o;
            o.x = (_Float16)(acc[r].x * dsc);
            o.y = (_Float16)(acc[r].y * dsc);
            o.z = (_Float16)(acc[r].z * dsc);
            o.w = (_Float16)(acc[r].w * dsc);
            hout4[n * 16 + fg] = o;
        }
    }
}

// ---------------- Aggregation: 8 edge slots, 16B half8 gathers, branchless ----------------

__global__ void aggregate_kernel(const half8* __restrict__ hwh, const int* __restrict__ csrOff,
                                 const int* __restrict__ csrSrc, const float* __restrict__ dis,
                                 const float* __restrict__ bias, float4* __restrict__ y4,
                                 float* __restrict__ sums, float* __restrict__ sumsq) {
    const int lane = threadIdx.x & 63;
    const int wid = threadIdx.x >> 6;
    const int o = lane >> 3;  // edge slot 0..7
    const int c = lane & 7;   // half8 column within the 64-half row
    const int wave = blockIdx.x * 4 + wid;
    const int nwaves = gridDim.x * 4;

    const float4 bv0 = ((const float4*)bias)[c * 2];
    const float4 bv1 = ((const float4*)bias)[c * 2 + 1];
    float sa[8], qa[8];
#pragma unroll
    for (int j = 0; j < 8; j++) { sa[j] = 0.f; qa[j] = 0.f; }

    int n = wave;
    int beg = 0, end = 0;
    if (n < N_NODES) { beg = csrOff[n]; end = csrOff[n + 1]; }
    while (n < N_NODES) {
        int nn = n + nwaves;
        int begN = 0, endN = 0;
        if (nn < N_NODES) { begN = csrOff[nn]; endN = csrOff[nn + 1]; }  // prefetch
        float d = dis[n];
        float acc[8];
        if (o == 0) {
            half8 s = hwh[(size_t)n * 8 + c];  // self loop
#pragma unroll
            for (int j = 0; j < 8; j++) acc[j] = (float)s[j];
        } else {
#pragma unroll
            for (int j = 0; j < 8; j++) acc[j] = 0.f;
        }
        int e = beg + o;
        while (e < end) {
            int s0 = csrSrc[e];       // always valid (e < end)
            int s1 = csrSrc[e + 8];   // csrSrc padded; clamp via select
            int j1 = (e + 8 < end) ? s1 : N_NODES;  // dummy zero row
            half8 h0 = hwh[(size_t)s0 * 8 + c];
            half8 h1 = hwh[(size_t)j1 * 8 + c];
#pragma unroll
            for (int j = 0; j < 8; j++) acc[j] += (float)h0[j] + (float)h1[j];
            e += 16;
        }
#pragma unroll
        for (int j = 0; j < 8; j++) {
            acc[j] += __shfl_xor(acc[j], 8, 64);
            acc[j] += __shfl_xor(acc[j], 16, 64);
            acc[j] += __shfl_xor(acc[j], 32, 64);
        }
        if (o == 0) {
            float val[8];
            val[0] = acc[0] * d + bv0.x; val[1] = acc[1] * d + bv0.y;
            val[2] = acc[2] * d + bv0.z; val[3] = acc[3] * d + bv0.w;
            val[4] = acc[4] * d + bv1.x; val[5] = acc[5] * d + bv1.y;
            val[6] = acc[6] * d + bv1.z; val[7] = acc[7] * d + bv1.w;
            float4 v0 = make_float4(val[0], val[1], val[2], val[3]);
            float4 v1 = make_float4(val[4], val[5], val[6], val[7]);
            y4[(size_t)n * 16 + c * 2] = v0;
            y4[(size_t)n * 16 + c * 2 + 1] = v1;
#pragma unroll
            for (int j = 0; j < 8; j++) { sa[j] += val[j]; qa[j] += val[j] * val[j]; }
        }
        n = nn; beg = begN; end = endN;
    }
    __shared__ float ls[4][64], lq[4][64];
    ls[wid][lane] = 0.f;
    lq[wid][lane] = 0.f;
    // same-wave program order: zeros land before the writes below
    if (o == 0) {
#pragma unroll
        for (int j = 0; j < 8; j++) { ls[wid][c * 8 + j] = sa[j]; lq[wid][c * 8 + j] = qa[j]; }
    }
    __syncthreads();
    if (wid == 0) {
        float S = ls[0][lane] + ls[1][lane] + ls[2][lane] + ls[3][lane];
        float Q = lq[0][lane] + lq[1][lane] + lq[2][lane] + lq[3][lane];
        atomicAdd(&sums[lane], S);
        atomicAdd(&sumsq[lane], Q);
    }
}

// ---------------- Pool + head ----------------

#define POOL_CHUNK 256
__global__ void pool_kernel(const float* __restrict__ y, const int* __restrict__ batch,
                            const float* __restrict__ scale, const float* __restrict__ shift,
                            float* __restrict__ pool, float* __restrict__ cnt) {
    int f = threadIdx.x & 63;
    int nl = threadIdx.x >> 6;
    int base = blockIdx.x * POOL_CHUNK;
    int endn = min(base + POOL_CHUNK, N_NODES);
    float sc = scale[f], sh = shift[f];
    int g_cur = -1;
    float acc = 0.f;
    float c_acc = 0.f;
    for (int n = base + nl; n < endn; n += 4) {
        int g = batch[n];
        float v = fmaxf(y[n * HID + f] * sc + sh, 0.f);
        if (g != g_cur) {
            if (g_cur >= 0) {
                atomicAdd(&pool[g_cur * HID + f], acc);
                if (f == 0) atomicAdd(&cnt[g_cur], c_acc);
            }
            g_cur = g;
            acc = 0.f;
            c_acc = 0.f;
        }
        acc += v;
        c_acc += 1.f;
    }
    if (g_cur >= 0) {
        atomicAdd(&pool[g_cur * HID + f], acc);
        if (f == 0) atomicAdd(&cnt[g_cur], c_acc);
    }
}

__global__ void head_kernel(const float* __restrict__ pool, const float* __restrict__ cnt,
                            const float* __restrict__ Wc1, const float* __restrict__ bc1,
                            const float* __restrict__ Wc2, const float* __restrict__ bc2,
                            float* __restrict__ out) {
    int g = blockIdx.x;
    int f = threadIdx.x;  // 64 threads
    __shared__ float p[64], z[64];
    float c = fmaxf(cnt[g], 1.0f);
    p[f] = pool[g * HID + f] / c;
    __syncthreads();
    float acc = bc1[f];
    for (int k = 0; k < 64; k++) acc += p[k] * Wc1[k * 64 + f];
    z[f] = fmaxf(acc, 0.f);
    __syncthreads();
    if (f < 2) {
        float o = bc2[f];
        for (int k = 0; k < 64; k++) o += z[k] * Wc2[k * 2 + f];
        out[g * 2 + f] = o;
    }
}

// ---------------- launch ----------------

extern "C" void kernel_launch(void* const* d_in, const int* in_sizes, int n_in,
                              void* d_out, int out_size, void* d_ws, size_t ws_size,
                              hipStream_t stream) {
    const float* x      = (const float*)d_in[0];
    const int*   ei     = (const int*)d_in[1];
    const int*   batch  = (const int*)d_in[2];
    const float* bn_in_g = (const float*)d_in[3];
    const float* bn_in_b = (const float*)d_in[4];
    const float* W0 = (const float*)d_in[5];
    const float* b0 = (const float*)d_in[6];
    const float* g0 = (const float*)d_in[7];
    const float* be0 = (const float*)d_in[8];
    const float* W1 = (const float*)d_in[9];
    const float* b1 = (const float*)d_in[10];
    const float* g1 = (const float*)d_in[11];
    const float* be1 = (const float*)d_in[12];
    const float* W2 = (const float*)d_in[13];
    const float* b2 = (const float*)d_in[14];
    const float* g2 = (const float*)d_in[15];
    const float* be2 = (const float*)d_in[16];
    const float* Wc1 = (const float*)d_in[17];
    const float* bc1 = (const float*)d_in[18];
    const float* Wc2 = (const float*)d_in[19];
    const float* bc2 = (const float*)d_in[20];
    float* out = (float*)d_out;

    char* w = (char*)d_ws;
    size_t off = 0;
    auto take = [&](size_t bytes) {
        size_t r = off;
        off += (bytes + 255) & ~(size_t)255;
        return r;
    };
    // ---- zero region (one memset) ----
    float* stats  = (float*)(w + take(4 * 256 * 4));
    float* pool   = (float*)(w + take((size_t)N_GRAPHS * HID * 4));
    float* cnt    = (float*)(w + take((size_t)N_GRAPHS * 4));
    int* bucketCnt = (int*)(w + take((size_t)NB_BUCKETS * 4));
    size_t zero_end = off;
    // ---- rest ----
    float* dis    = (float*)(w + take((size_t)N_NODES * 4));
    int* csrOff   = (int*)(w + take((size_t)(N_NODES + 1) * 4));
    int* csrSrc   = (int*)(w + take((size_t)(N_EDGES + 16) * 4));  // +pad for e+8 reads
    int* bucketBase = (int*)(w + take((size_t)(NB_BUCKETS + 1) * 4));
    _Float16* hwBuf = (_Float16*)(w + take((size_t)(N_NODES + 1) * HID * 2));  // +dummy row
    float* yBuf   = (float*)(w + take((size_t)N_NODES * HID * 4));
    int* regions  = (int*)hwBuf;  // alias: regions (6.4 MB) used only before gemm16
    (void)ws_size; (void)n_in; (void)in_sizes; (void)out_size;

    hipMemsetAsync(w, 0, zero_end, stream);

    const int nbBin  = (N_EDGES + BIN_TILE - 1) / BIN_TILE;  // 293
    const int nbG16  = (N_NODES + GEMM_ROWS - 1) / GEMM_ROWS;
    const int nbG64  = (N_NODES + G64_ROWS - 1) / G64_ROWS;
    const int nbAgg  = 4096;

    // CSR build (bucketed)
    bin_kernel<<<nbBin, 256, 0, stream>>>(ei, bucketCnt, regions);
    bucket_scan<<<1, 512, 0, stream>>>(bucketCnt, bucketBase);
    build_kernel<<<NB_BUCKETS, 256, 0, stream>>>(regions, bucketCnt, bucketBase,
                                                 csrOff, csrSrc, dis);

    float* s0 = stats + 0 * 256;
    float* s1 = stats + 1 * 256;
    float* s2 = stats + 2 * 256;
    float* s3 = stats + 3 * 256;

    // input BN (also zeroes hwBuf dummy row)
    stats_x<<<256, 256, 0, stream>>>(x, s0, s0 + 64, hwBuf);
    finalize_bn<<<1, 64, 0, stream>>>(s0, s0 + 64, bn_in_g, bn_in_b, s0 + 128, s0 + 192, IN_DIM);

    // layer 0
    gemm16_kernel<<<nbG16, 256, 0, stream>>>(x, W0, s0 + 128, s0 + 192, dis, hwBuf);
    aggregate_kernel<<<nbAgg, 256, 0, stream>>>((const half8*)hwBuf, csrOff, csrSrc, dis, b0,
                                                (float4*)yBuf, s1, s1 + 64);
    finalize_bn<<<1, 64, 0, stream>>>(s1, s1 + 64, g0, be0, s1 + 128, s1 + 192, HID);

    // layer 1
    gemm64_kernel<<<nbG64, 256, 0, stream>>>(yBuf, W1, s1 + 128, s1 + 192, dis, hwBuf);
    aggregate_kernel<<<nbAgg, 256, 0, stream>>>((const half8*)hwBuf, csrOff, csrSrc, dis, b1,
                                                (float4*)yBuf, s2, s2 + 64);
    finalize_bn<<<1, 64, 0, stream>>>(s2, s2 + 64, g1, be1, s2 + 128, s2 + 192, HID);

    // layer 2
    gemm64_kernel<<<nbG64, 256, 0, stream>>>(yBuf, W2, s2 + 128, s2 + 192, dis, hwBuf);
    aggregate_kernel<<<nbAgg, 256, 0, stream>>>((const half8*)hwBuf, csrOff, csrSrc, dis, b2,
                                                (float4*)yBuf, s3, s3 + 64);
    finalize_bn<<<1, 64, 0, stream>>>(s3, s3 + 64, g2, be2, s3 + 128, s3 + 192, HID);

    // pool + head
    const int nbPool = (N_NODES + POOL_CHUNK - 1) / POOL_CHUNK;
    pool_kernel<<<nbPool, 256, 0, stream>>>(yBuf, batch, s3 + 128, s3 + 192, pool, cnt);
    head_kernel<<<N_GRAPHS, 64, 0, stream>>>(pool, cnt, Wc1, bc1, Wc2, bc2, out);
}

// Round 6
// 543.286 us; speedup vs baseline: 1.1489x; 1.1054x over previous
//
#include <hip/hip_runtime.h>
#include <hip/hip_bf16.h>

#define N_NODES 100000
#define N_EDGES 1200000
#define N_GRAPHS 512
#define HID 64
#define IN_DIM 16
#define EPS 1e-5f

#define NB_BUCKETS 391   // ceil(N_NODES / BUCKET_SPAN)
#define BUCKET_SPAN 256  // dst >> 8
#define REGION 4096      // per-bucket region capacity (avg real fill ~3069)
#define BIN_TILE 4096    // edges per bin block
#define CSR_LEN (N_EDGES + N_NODES)  // self-loops folded in

// ---------------- CSR build (bucketed, LDS-built, self-loops included) ----------------

__global__ void bin_kernel(const int* __restrict__ ei, int* __restrict__ bucketCnt,
                           int* __restrict__ regions) {
    __shared__ int hist[NB_BUCKETS], basem[NB_BUCKETS], cur[NB_BUCKETS];
    int t = threadIdx.x;
    for (int i = t; i < NB_BUCKETS; i += 256) { hist[i] = 0; cur[i] = 0; }
    __syncthreads();
    int e0 = blockIdx.x * BIN_TILE;
    int srcs[16], dsts[16];
#pragma unroll
    for (int i = 0; i < 16; i++) {
        int e = e0 + t + i * 256;
        if (e < N_EDGES) {
            srcs[i] = ei[e];
            dsts[i] = ei[N_EDGES + e];
            atomicAdd(&hist[dsts[i] >> 8], 1);
        } else {
            dsts[i] = -1;
        }
    }
    __syncthreads();
    for (int i = t; i < NB_BUCKETS; i += 256) {
        int h = hist[i];
        basem[i] = h ? atomicAdd(&bucketCnt[i], h) : 0;
    }
    __syncthreads();
#pragma unroll
    for (int i = 0; i < 16; i++) {
        if (dsts[i] >= 0) {
            int b = dsts[i] >> 8;
            int pos = basem[b] + atomicAdd(&cur[b], 1);
            if (pos < REGION)
                regions[b * REGION + pos] = srcs[i] | ((dsts[i] & 255) << 17);
        }
    }
}

// One block per bucket. Computes its own prefix base (sum of earlier buckets),
// adds self-loop records, builds sorted slice in LDS, streams out coalesced.
__global__ void build_kernel(const int* __restrict__ regions, const int* __restrict__ bucketCnt,
                             int* __restrict__ csrOff, int* __restrict__ csrSrc,
                             float* __restrict__ dis) {
    __shared__ int deg[256], off[256], cur[256];
    __shared__ int slice[REGION + 256];
    __shared__ int sTot, sBase;
    int b = blockIdx.x, t = threadIdx.x;
    // prefix base: sum of real counts of buckets < b, plus b*256 self loops
    {
        int s = 0;
        for (int i = t; i < NB_BUCKETS; i += 256)
            if (i < b) s += min(bucketCnt[i], REGION);
        deg[t] = s;  // reuse deg[] as scratch for the reduce
        __syncthreads();
        for (int k = 128; k > 0; k >>= 1) {
            if (t < k) deg[t] += deg[t + k];
            __syncthreads();
        }
        if (t == 0) sBase = deg[0] + b * BUCKET_SPAN;
        __syncthreads();
    }
    int bb = sBase;
    int cnt = min(bucketCnt[b], REGION);
    int nbase = b * BUCKET_SPAN;
    int n = nbase + t;
    bool valid = (n < N_NODES);
    deg[t] = valid ? 1 : 0;  // self loop
    __syncthreads();
    for (int i = t; i < cnt; i += 256) {
        int rec = regions[b * REGION + i];
        atomicAdd(&deg[rec >> 17], 1);
    }
    __syncthreads();
    int d = deg[t];
    off[t] = d;
    __syncthreads();
    for (int s = 1; s < 256; s <<= 1) {
        int v = (t >= s) ? off[t - s] : 0;
        __syncthreads();
        off[t] += v;
        __syncthreads();
    }
    int excl = off[t] - d;
    if (valid) {
        csrOff[n] = bb + excl;
        dis[n] = rsqrtf((float)d);  // d includes self loop
    }
    if (b == 0 && t == 0) csrOff[N_NODES] = CSR_LEN;
    if (t == 255) sTot = off[255];
    cur[t] = excl;
    __syncthreads();
    if (valid) {  // self record
        int pos = atomicAdd(&cur[t], 1);
        slice[pos] = n;
    }
    for (int i = t; i < cnt; i += 256) {
        int rec = regions[b * REGION + i];
        int pos = atomicAdd(&cur[rec >> 17], 1);
        slice[pos] = rec & 0x1FFFF;
    }
    __syncthreads();
    int tot = sTot;
    for (int i = t; i < tot; i += 256) csrSrc[bb + i] = slice[i];
}

// ---------------- BN statistics over x (also zeroes the dummy gather row) ----------------

__global__ void stats_x(const float* __restrict__ x, float* __restrict__ sums,
                        float* __restrict__ sumsq, float* __restrict__ hwBuf) {
    __shared__ float ls[16], lq[16];
    int t = threadIdx.x;
    if (blockIdx.x == 0 && t < 16)
        ((float4*)(hwBuf + (size_t)N_NODES * HID))[t] = make_float4(0.f, 0.f, 0.f, 0.f);
    if (t < 16) { ls[t] = 0.f; lq[t] = 0.f; }
    __syncthreads();
    float s = 0.f, q = 0.f;
    const int total = N_NODES * IN_DIM;
    for (int i = blockIdx.x * blockDim.x + t; i < total; i += gridDim.x * blockDim.x) {
        float v = x[i];
        s += v; q += v * v;
    }
    int k = t & 15;
    atomicAdd(&ls[k], s);
    atomicAdd(&lq[k], q);
    __syncthreads();
    if (t < 16) { atomicAdd(&sums[t], ls[t]); atomicAdd(&sumsq[t], lq[t]); }
}

__device__ __forceinline__ void bn_coef(const float* sums, const float* sumsq,
                                        const float* gamma, const float* beta, int k,
                                        float& sc, float& sh) {
    const float invn = 1.0f / (float)N_NODES;
    float m = sums[k] * invn;
    float var = sumsq[k] * invn - m * m;
    float rs = rsqrtf(var + EPS);
    sc = gamma[k] * rs;
    sh = beta[k] - m * sc;
}

// ---------------- GEMMs (BN finalize + affine fused; f32 message output) ----------------

#define GEMM_ROWS 32

__global__ void gemm16_kernel(const float* __restrict__ x, const float* __restrict__ W,
                              const float* __restrict__ sums, const float* __restrict__ sumsq,
                              const float* __restrict__ gamma, const float* __restrict__ beta,
                              const float* __restrict__ dis, float* __restrict__ hout) {
    __shared__ float Ws[IN_DIM][HID];
    __shared__ float xs[GEMM_ROWS][IN_DIM];
    __shared__ float sc16[16], sh16[16];
    int t = threadIdx.x, f = t & 63, nl = t >> 6;
    if (t < 16) bn_coef(sums, sumsq, gamma, beta, t, sc16[t], sh16[t]);
    for (int i = t; i < IN_DIM * HID; i += 256) Ws[i >> 6][i & 63] = W[i];
    __syncthreads();
    int base = blockIdx.x * GEMM_ROWS;
    for (int i = t; i < GEMM_ROWS * IN_DIM; i += 256) {
        int r = i >> 4, k = i & 15;
        int n = base + r;
        float v = 0.f;
        if (n < N_NODES) v = x[n * IN_DIM + k] * sc16[k] + sh16[k];
        xs[r][k] = v;
    }
    __syncthreads();
    float acc[8];
#pragma unroll
    for (int r = 0; r < 8; r++) acc[r] = 0.f;
    for (int k = 0; k < IN_DIM; k++) {
        float wk = Ws[k][f];
#pragma unroll
        for (int r = 0; r < 8; r++) acc[r] += xs[r * 4 + nl][k] * wk;
    }
#pragma unroll
    for (int r = 0; r < 8; r++) {
        int n = base + r * 4 + nl;
        if (n < N_NODES) hout[n * HID + f] = acc[r] * dis[n];
    }
}

#define G64_ROWS 128
__global__ void gemm64_kernel(const float* __restrict__ hin, const float* __restrict__ W,
                              const float* __restrict__ sums, const float* __restrict__ sumsq,
                              const float* __restrict__ gamma, const float* __restrict__ beta,
                              const float* __restrict__ dis, float* __restrict__ hout) {
    __shared__ float Ws[HID * HID];          // [k][f], f contiguous
    __shared__ float hs[G64_ROWS][HID + 1];  // +1 pad
    __shared__ float scb[64], shb[64];
    int t = threadIdx.x;
    int fg = t & 15;
    int rg = t >> 4;
    int base = blockIdx.x * G64_ROWS;

    if (t < 64) bn_coef(sums, sumsq, gamma, beta, t, scb[t], shb[t]);
    {
        const float4* W4 = (const float4*)W;
        float4* Ws4 = (float4*)Ws;
        for (int i = t; i < HID * HID / 4; i += 256) Ws4[i] = W4[i];
    }
    __syncthreads();
    {
        const float4* hin4 = (const float4*)hin;
        for (int i = t; i < G64_ROWS * 16; i += 256) {
            int r = i >> 4, c = i & 15;
            int n = base + r;
            float4 v = make_float4(0.f, 0.f, 0.f, 0.f);
            if (n < N_NODES) {
                float4 h = hin4[n * 16 + c];
                v.x = fmaxf(h.x * scb[c * 4 + 0] + shb[c * 4 + 0], 0.f);
                v.y = fmaxf(h.y * scb[c * 4 + 1] + shb[c * 4 + 1], 0.f);
                v.z = fmaxf(h.z * scb[c * 4 + 2] + shb[c * 4 + 2], 0.f);
                v.w = fmaxf(h.w * scb[c * 4 + 3] + shb[c * 4 + 3], 0.f);
            }
            hs[r][c * 4 + 0] = v.x;
            hs[r][c * 4 + 1] = v.y;
            hs[r][c * 4 + 2] = v.z;
            hs[r][c * 4 + 3] = v.w;
        }
    }
    __syncthreads();

    float4 acc[8];
#pragma unroll
    for (int r = 0; r < 8; r++) acc[r] = make_float4(0.f, 0.f, 0.f, 0.f);
    const float4* Ws4 = (const float4*)Ws;
    for (int k = 0; k < HID; k++) {
        float4 wk = Ws4[k * 16 + fg];
#pragma unroll
        for (int r = 0; r < 8; r++) {
            float h = hs[rg * 8 + r][k];
            acc[r].x += h * wk.x;
            acc[r].y += h * wk.y;
            acc[r].z += h * wk.z;
            acc[r].w += h * wk.w;
        }
    }
    float4* hout4 = (float4*)hout;
#pragma unroll
    for (int r = 0; r < 8; r++) {
        int n = base + rg * 8 + r;
        if (n < N_NODES) {
            float dsc = dis[n];
            float4 o = acc[r];
            o.x *= dsc; o.y *= dsc; o.z *= dsc; o.w *= dsc;
            hout4[n * 16 + fg] = o;
        }
    }
}

// ---------------- Aggregation: pair-interleaved, depth-4 gathers, f32 ----------------

__global__ void aggregate_kernel(const float4* __restrict__ hw4, const int* __restrict__ csrOff,
                                 const int* __restrict__ csrSrc, const float* __restrict__ dis,
                                 const float* __restrict__ bias, float4* __restrict__ y4,
                                 float* __restrict__ sums, float* __restrict__ sumsq) {
    const int lane = threadIdx.x & 63;
    const int wid = threadIdx.x >> 6;
    const int q = lane >> 4;   // edge slot 0..3
    const int fl = lane & 15;  // float4 column
    const int wave = blockIdx.x * 4 + wid;
    const int nwaves = gridDim.x * 4;

    const float4 bias4 = ((const float4*)bias)[fl];
    float4 s_acc = make_float4(0.f, 0.f, 0.f, 0.f);
    float4 q_acc = make_float4(0.f, 0.f, 0.f, 0.f);

    for (int nA = wave; nA < N_NODES; nA += 2 * nwaves) {
        int nB = nA + nwaves;
        bool hasB = (nB < N_NODES);
        int begA = csrOff[nA], endA = csrOff[nA + 1];
        int begB = 0, endB = 0;
        if (hasB) { begB = csrOff[nB]; endB = csrOff[nB + 1]; }
        float4 accA = make_float4(0.f, 0.f, 0.f, 0.f);
        float4 accB = make_float4(0.f, 0.f, 0.f, 0.f);
        int eA = begA + q, eB = begB + q;
        int iA0 = (eA < endA) ? csrSrc[eA] : N_NODES;
        int iA1 = (eA + 4 < endA) ? csrSrc[eA + 4] : N_NODES;
        int iB0 = (eB < endB) ? csrSrc[eB] : N_NODES;
        int iB1 = (eB + 4 < endB) ? csrSrc[eB + 4] : N_NODES;
        while (eA < endA || eB < endB) {
            int jA0 = iA0, jA1 = iA1, jB0 = iB0, jB1 = iB1;
            eA += 8; eB += 8;
            iA0 = (eA < endA) ? csrSrc[eA] : N_NODES;
            iA1 = (eA + 4 < endA) ? csrSrc[eA + 4] : N_NODES;
            iB0 = (eB < endB) ? csrSrc[eB] : N_NODES;
            iB1 = (eB + 4 < endB) ? csrSrc[eB + 4] : N_NODES;
            float4 vA0 = hw4[(size_t)jA0 * 16 + fl];
            float4 vA1 = hw4[(size_t)jA1 * 16 + fl];
            float4 vB0 = hw4[(size_t)jB0 * 16 + fl];
            float4 vB1 = hw4[(size_t)jB1 * 16 + fl];
            accA.x += vA0.x + vA1.x; accA.y += vA0.y + vA1.y;
            accA.z += vA0.z + vA1.z; accA.w += vA0.w + vA1.w;
            accB.x += vB0.x + vB1.x; accB.y += vB0.y + vB1.y;
            accB.z += vB0.z + vB1.z; accB.w += vB0.w + vB1.w;
        }
        accA.x += __shfl_xor(accA.x, 16, 64);
        accA.y += __shfl_xor(accA.y, 16, 64);
        accA.z += __shfl_xor(accA.z, 16, 64);
        accA.w += __shfl_xor(accA.w, 16, 64);
        accA.x += __shfl_xor(accA.x, 32, 64);
        accA.y += __shfl_xor(accA.y, 32, 64);
        accA.z += __shfl_xor(accA.z, 32, 64);
        accA.w += __shfl_xor(accA.w, 32, 64);
        accB.x += __shfl_xor(accB.x, 16, 64);
        accB.y += __shfl_xor(accB.y, 16, 64);
        accB.z += __shfl_xor(accB.z, 16, 64);
        accB.w += __shfl_xor(accB.w, 16, 64);
        accB.x += __shfl_xor(accB.x, 32, 64);
        accB.y += __shfl_xor(accB.y, 32, 64);
        accB.z += __shfl_xor(accB.z, 32, 64);
        accB.w += __shfl_xor(accB.w, 32, 64);
        if (q == 0) {
            float dA = dis[nA];
            float4 valA;
            valA.x = accA.x * dA + bias4.x;
            valA.y = accA.y * dA + bias4.y;
            valA.z = accA.z * dA + bias4.z;
            valA.w = accA.w * dA + bias4.w;
            y4[(size_t)nA * 16 + fl] = valA;
            s_acc.x += valA.x; s_acc.y += valA.y; s_acc.z += valA.z; s_acc.w += valA.w;
            q_acc.x += valA.x * valA.x; q_acc.y += valA.y * valA.y;
            q_acc.z += valA.z * valA.z; q_acc.w += valA.w * valA.w;
            if (hasB) {
                float dB = dis[nB];
                float4 valB;
                valB.x = accB.x * dB + bias4.x;
                valB.y = accB.y * dB + bias4.y;
                valB.z = accB.z * dB + bias4.z;
                valB.w = accB.w * dB + bias4.w;
                y4[(size_t)nB * 16 + fl] = valB;
                s_acc.x += valB.x; s_acc.y += valB.y; s_acc.z += valB.z; s_acc.w += valB.w;
                q_acc.x += valB.x * valB.x; q_acc.y += valB.y * valB.y;
                q_acc.z += valB.z * valB.z; q_acc.w += valB.w * valB.w;
            }
        }
    }
    __shared__ float ls[4][64], lq[4][64];
    ls[wid][lane] = 0.f;
    lq[wid][lane] = 0.f;
    if (q == 0) {
        ls[wid][fl * 4 + 0] = s_acc.x; ls[wid][fl * 4 + 1] = s_acc.y;
        ls[wid][fl * 4 + 2] = s_acc.z; ls[wid][fl * 4 + 3] = s_acc.w;
        lq[wid][fl * 4 + 0] = q_acc.x; lq[wid][fl * 4 + 1] = q_acc.y;
        lq[wid][fl * 4 + 2] = q_acc.z; lq[wid][fl * 4 + 3] = q_acc.w;
    }
    __syncthreads();
    if (wid == 0) {
        float S = ls[0][lane] + ls[1][lane] + ls[2][lane] + ls[3][lane];
        float Q = lq[0][lane] + lq[1][lane] + lq[2][lane] + lq[3][lane];
        atomicAdd(&sums[lane], S);
        atomicAdd(&sumsq[lane], Q);
    }
}

// ---------------- Pool (BN finalize fused) + head ----------------

#define POOL_CHUNK 256
__global__ void pool_kernel(const float* __restrict__ y, const int* __restrict__ batch,
                            const float* __restrict__ sums, const float* __restrict__ sumsq,
                            const float* __restrict__ gamma, const float* __restrict__ beta,
                            float* __restrict__ pool, float* __restrict__ cnt) {
    int f = threadIdx.x & 63;
    int nl = threadIdx.x >> 6;
    float sc, sh;
    bn_coef(sums, sumsq, gamma, beta, f, sc, sh);
    int base = blockIdx.x * POOL_CHUNK;
    int endn = min(base + POOL_CHUNK, N_NODES);
    int g_cur = -1;
    float acc = 0.f;
    float c_acc = 0.f;
    for (int n = base + nl; n < endn; n += 4) {
        int g = batch[n];
        float v = fmaxf(y[n * HID + f] * sc + sh, 0.f);
        if (g != g_cur) {
            if (g_cur >= 0) {
                atomicAdd(&pool[g_cur * HID + f], acc);
                if (f == 0) atomicAdd(&cnt[g_cur], c_acc);
            }
            g_cur = g;
            acc = 0.f;
            c_acc = 0.f;
        }
        acc += v;
        c_acc += 1.f;
    }
    if (g_cur >= 0) {
        atomicAdd(&pool[g_cur * HID + f], acc);
        if (f == 0) atomicAdd(&cnt[g_cur], c_acc);
    }
}

__global__ void head_kernel(const float* __restrict__ pool, const float* __restrict__ cnt,
                            const float* __restrict__ Wc1, const float* __restrict__ bc1,
                            const float* __restrict__ Wc2, const float* __restrict__ bc2,
                            float* __restrict__ out) {
    int g = blockIdx.x;
    int f = threadIdx.x;  // 64 threads
    __shared__ float p[64], z[64];
    float c = fmaxf(cnt[g], 1.0f);
    p[f] = pool[g * HID + f] / c;
    __syncthreads();
    float acc = bc1[f];
    for (int k = 0; k < 64; k++) acc += p[k] * Wc1[k * 64 + f];
    z[f] = fmaxf(acc, 0.f);
    __syncthreads();
    if (f < 2) {
        float o = bc2[f];
        for (int k = 0; k < 64; k++) o += z[k] * Wc2[k * 2 + f];
        out[g * 2 + f] = o;
    }
}

// ---------------- launch ----------------

extern "C" void kernel_launch(void* const* d_in, const int* in_sizes, int n_in,
                              void* d_out, int out_size, void* d_ws, size_t ws_size,
                              hipStream_t stream) {
    const float* x      = (const float*)d_in[0];
    const int*   ei     = (const int*)d_in[1];
    const int*   batch  = (const int*)d_in[2];
    const float* bn_in_g = (const float*)d_in[3];
    const float* bn_in_b = (const float*)d_in[4];
    const float* W0 = (const float*)d_in[5];
    const float* b0 = (const float*)d_in[6];
    const float* g0 = (const float*)d_in[7];
    const float* be0 = (const float*)d_in[8];
    const float* W1 = (const float*)d_in[9];
    const float* b1 = (const float*)d_in[10];
    const float* g1 = (const float*)d_in[11];
    const float* be1 = (const float*)d_in[12];
    const float* W2 = (const float*)d_in[13];
    const float* b2 = (const float*)d_in[14];
    const float* g2 = (const float*)d_in[15];
    const float* be2 = (const float*)d_in[16];
    const float* Wc1 = (const float*)d_in[17];
    const float* bc1 = (const float*)d_in[18];
    const float* Wc2 = (const float*)d_in[19];
    const float* bc2 = (const float*)d_in[20];
    float* out = (float*)d_out;

    char* w = (char*)d_ws;
    size_t off = 0;
    auto take = [&](size_t bytes) {
        size_t r = off;
        off += (bytes + 255) & ~(size_t)255;
        return r;
    };
    // ---- zero region (one memset) ----
    float* stats  = (float*)(w + take(4 * 256 * 4));  // slot l: [sums 64][sumsq 64]
    float* pool   = (float*)(w + take((size_t)N_GRAPHS * HID * 4));
    float* cnt    = (float*)(w + take((size_t)N_GRAPHS * 4));
    int* bucketCnt = (int*)(w + take((size_t)NB_BUCKETS * 4));
    size_t zero_end = off;
    // ---- rest ----
    float* dis    = (float*)(w + take((size_t)N_NODES * 4));
    int* csrOff   = (int*)(w + take((size_t)(N_NODES + 1) * 4));
    int* csrSrc   = (int*)(w + take((size_t)(CSR_LEN + 16) * 4));
    float* hwBuf  = (float*)(w + take((size_t)(N_NODES + 1) * HID * 4));  // +dummy zero row
    float* yBuf   = (float*)(w + take((size_t)N_NODES * HID * 4));
    int* regions  = (int*)hwBuf;  // alias: regions (6.4 MB) used only before gemm16
    (void)ws_size; (void)n_in; (void)in_sizes; (void)out_size;

    hipMemsetAsync(w, 0, zero_end, stream);

    const int nbBin  = (N_EDGES + BIN_TILE - 1) / BIN_TILE;  // 293
    const int nbG16  = (N_NODES + GEMM_ROWS - 1) / GEMM_ROWS;
    const int nbG64  = (N_NODES + G64_ROWS - 1) / G64_ROWS;
    const int nbAgg  = 2048;

    // CSR build (bucketed; self-loops folded in)
    bin_kernel<<<nbBin, 256, 0, stream>>>(ei, bucketCnt, regions);
    build_kernel<<<NB_BUCKETS, 256, 0, stream>>>(regions, bucketCnt, csrOff, csrSrc, dis);

    float* s0 = stats + 0 * 256;
    float* s1 = stats + 1 * 256;
    float* s2 = stats + 2 * 256;
    float* s3 = stats + 3 * 256;

    // input BN stats (also zeroes hwBuf dummy row)
    stats_x<<<256, 256, 0, stream>>>(x, s0, s0 + 64, hwBuf);

    // layer 0
    gemm16_kernel<<<nbG16, 256, 0, stream>>>(x, W0, s0, s0 + 64, bn_in_g, bn_in_b, dis, hwBuf);
    aggregate_kernel<<<nbAgg, 256, 0, stream>>>((const float4*)hwBuf, csrOff, csrSrc, dis, b0,
                                                (float4*)yBuf, s1, s1 + 64);
    // layer 1
    gemm64_kernel<<<nbG64, 256, 0, stream>>>(yBuf, W1, s1, s1 + 64, g0, be0, dis, hwBuf);
    aggregate_kernel<<<nbAgg, 256, 0, stream>>>((const float4*)hwBuf, csrOff, csrSrc, dis, b1,
                                                (float4*)yBuf, s2, s2 + 64);
    // layer 2
    gemm64_kernel<<<nbG64, 256, 0, stream>>>(yBuf, W2, s2, s2 + 64, g1, be1, dis, hwBuf);
    aggregate_kernel<<<nbAgg, 256, 0, stream>>>((const float4*)hwBuf, csrOff, csrSrc, dis, b2,
                                                (float4*)yBuf, s3, s3 + 64);

    // pool + head
    const int nbPool = (N_NODES + POOL_CHUNK - 1) / POOL_CHUNK;
    pool_kernel<<<nbPool, 256, 0, stream>>>(yBuf, batch, s3, s3 + 64, g2, be2, pool, cnt);
    head_kernel<<<N_GRAPHS, 64, 0, stream>>>(pool, cnt, Wc1, bc1, Wc2, bc2, out);
}